// Round 8
// baseline (5703.910 us; speedup 1.0000x reference)
//
#include <hip/hip_runtime.h>
#include <hip/hip_bf16.h>
#include <cmath>

// GMM E-step: N=131072, K=64, D=256.
// Round 8: barrier-free free-running waves. A staged once to LDS (64KB,
// fragment-linear, read-only). B global->reg depth-3 pipeline. Per-k
// cross-wave reduce replaced by fp32 atomicAdd of per-wc partials into
// the wlp buffer (zeroed via hipMemsetAsync). Zero barriers in the loop;
// s_setprio around the MFMA cluster.

typedef unsigned short ushort_t;
typedef __attribute__((ext_vector_type(4))) float f32x4;
typedef __attribute__((ext_vector_type(8))) short bf16x8;

constexpr int N_ = 131072;
constexpr int K_ = 64;
constexpr int D_ = 256;
constexpr int BM = 128;                 // rows per block
constexpr int NBLK = N_ / BM;           // 1024 blocks
constexpr int NSUB = 256;               // total 64-k substeps (K*D/64)

// ---------- helpers ----------
__device__ __forceinline__ ushort_t f2bf(float v) {
  unsigned u = __float_as_uint(v);
  u += 0x7FFFu + ((u >> 16) & 1u);  // RNE
  return (ushort_t)(u >> 16);
}

__device__ __forceinline__ void gld16(const ushort_t* g, ushort_t* l) {
  __builtin_amdgcn_global_load_lds(
      (const __attribute__((address_space(1))) unsigned int*)g,
      (__attribute__((address_space(3))) unsigned int*)l, 16, 0, 0);
}

// ---------- prep: X fp32 -> bf16 A-fragment image ----------
// e = ((T*8 + mm)*8 + kc)*512 + lane*8 + j  holds
//   bf16( X[T*128 + mm*16 + (lane&15)][kc*32 + (lane>>4)*8 + j] )
__global__ void prep_x(const float* __restrict__ X, ushort_t* __restrict__ Xb) {
  for (int e = blockIdx.x * blockDim.x + threadIdx.x; e < N_ * D_;
       e += gridDim.x * blockDim.x) {
    int j = e & 7;
    int lane = (e >> 3) & 63;
    int kc = (e >> 9) & 7;
    int mm = (e >> 12) & 7;
    int T = e >> 15;
    int row = T * 128 + mm * 16 + (lane & 15);
    int col = kc * 32 + (lane >> 4) * 8 + j;
    Xb[e] = f2bf(X[(size_t)row * D_ + col]);
  }
}

// ---------- prep: P fp32 -> bf16 B-fragment image ----------
// fr = ((g*4 + wc)*8 + ki*4 + n);  e = fr*512 + lane*8 + j holds
//   bf16( P[k][s*64 + ki*32 + (lane>>4)*8 + j][wc*64 + n*16 + (lane&15)] )
__global__ void prep_p(const float* __restrict__ P, ushort_t* __restrict__ Pb) {
  for (int e = blockIdx.x * blockDim.x + threadIdx.x; e < K_ * D_ * D_;
       e += gridDim.x * blockDim.x) {
    int j = e & 7;
    int lane = (e >> 3) & 63;
    int n = (e >> 9) & 3;
    int ki = (e >> 11) & 1;
    int wc = (e >> 12) & 3;
    int s = (e >> 14) & 3;
    int k = e >> 16;
    int row_p = s * 64 + ki * 32 + (lane >> 4) * 8 + j;
    int col_p = wc * 64 + n * 16 + (lane & 15);
    Pb[e] = f2bf(P[((size_t)k * D_ + row_p) * D_ + col_p]);
  }
}

// ---------- prep: t[k][j] = sum_i mu[k][i]*P[k][i][j];  C[k] ----------
__global__ void prep_t(const float* __restrict__ P, const float* __restrict__ mu,
                       const float* __restrict__ w, float* __restrict__ t,
                       float* __restrict__ C) {
  int k = blockIdx.x, j = threadIdx.x;
  const float* Pk = P + (size_t)k * D_ * D_;
  const float* muk = mu + (size_t)k * D_;
  float acc = 0.f;
  for (int i = 0; i < D_; ++i) acc += muk[i] * Pk[(size_t)i * D_ + j];
  t[k * D_ + j] = acc;
  __shared__ float red[D_];
  red[j] = logf(Pk[(size_t)j * D_ + j]);
  __syncthreads();
  for (int s = 128; s > 0; s >>= 1) {
    if (j < s) red[j] += red[j + s];
    __syncthreads();
  }
  if (j == 0)
    C[k] = red[0] + logf(w[k]) - 0.5f * (float)D_ * logf(2.0f * (float)M_PI);
}

// ---------- main: A in LDS, B depth-3 pipeline, atomic partials ----------
__global__ __launch_bounds__(512, 2) void gmm_main(
    const ushort_t* __restrict__ Xb, const ushort_t* __restrict__ Pb,
    const float* __restrict__ tvec,
    float* __restrict__ wlp /* [N][K], pre-zeroed; accumulates raw sq */) {
  __shared__ __align__(16) ushort_t Al[32768];  // 64 KiB A fragments

  const int tid = threadIdx.x;
  const int T = blockIdx.x;

  const int wid = tid >> 6, lane = tid & 63;
  const int wr = wid >> 2, wc = wid & 3;  // wave tile: 64 rows x 64 cols
  const int lc = lane & 15, lg = lane >> 4;

  // ---- stage A once: 64 KiB, fragment-linear ----
  const ushort_t* Ag = Xb + (size_t)T * 32768;
#pragma unroll
  for (int it = 0; it < 8; ++it) {
    int off = (it * 512 + tid) * 8;
    gld16(Ag + off, &Al[off]);
  }
  asm volatile("s_waitcnt vmcnt(0)" ::: "memory");
  __builtin_amdgcn_s_barrier();  // the only barrier in the kernel

  // ---- B register pipeline: depth 3, 4 buffers, static indices ----
  bf16x8 B[4][8];
#pragma unroll
  for (int pg = 0; pg < 3; ++pg) {
    const ushort_t* gb = Pb + (size_t)pg * 16384 + (size_t)wc * 4096 + lane * 8;
#pragma unroll
    for (int f = 0; f < 8; ++f) B[pg][f] = *(const bf16x8*)(gb + f * 512);
  }

#pragma unroll 1
  for (int k = 0; k < K_; ++k) {
    float tv[4];
#pragma unroll
    for (int n = 0; n < 4; ++n) tv[n] = tvec[k * D_ + wc * 64 + n * 16 + lc];

    f32x4 acc[4][4];
#pragma unroll
    for (int m = 0; m < 4; ++m)
#pragma unroll
      for (int n = 0; n < 4; ++n) acc[m][n] = (f32x4){0.f, 0.f, 0.f, 0.f};

#pragma unroll
    for (int s = 0; s < 4; ++s) {
      const int gp = k * 4 + s + 3;  // prefetch 3 substeps ahead
      if (gp < NSUB) {
        const ushort_t* gb =
            Pb + (size_t)gp * 16384 + (size_t)wc * 4096 + lane * 8;
#pragma unroll
        for (int f = 0; f < 8; ++f)
          B[(s + 3) & 3][f] = *(const bf16x8*)(gb + f * 512);
      }
      __builtin_amdgcn_s_setprio(1);
#pragma unroll
      for (int ki = 0; ki < 2; ++ki) {
#pragma unroll
        for (int m = 0; m < 4; ++m) {
          const int fA = (wr * 4 + m) * 8 + s * 2 + ki;
          bf16x8 a = *(const bf16x8*)&Al[fA * 512 + lane * 8];
#pragma unroll
          for (int n = 0; n < 4; ++n)
            acc[m][n] = __builtin_amdgcn_mfma_f32_16x16x32_bf16(
                a, B[s][ki * 4 + n], acc[m][n], 0, 0, 0);
        }
      }
      __builtin_amdgcn_s_setprio(0);
    }

    // epilogue: per-wc partial of sq, atomically accumulated into wlp.
    // No barrier, no LDS write; waves free-run.
#pragma unroll
    for (int m = 0; m < 4; ++m) {
#pragma unroll
      for (int r = 0; r < 4; ++r) {
        float sfl = 0.f;
#pragma unroll
        for (int n = 0; n < 4; ++n) {
          float d = acc[m][n][r] - tv[n];
          sfl += d * d;
        }
        sfl += __shfl_xor(sfl, 1, 64);
        sfl += __shfl_xor(sfl, 2, 64);
        sfl += __shfl_xor(sfl, 4, 64);
        sfl += __shfl_xor(sfl, 8, 64);
        if (lc == 0) {
          int row = T * BM + wr * 64 + m * 16 + lg * 4 + r;
          (void)__hip_atomic_fetch_add(&wlp[(size_t)row * K_ + k], sfl,
                                       __ATOMIC_RELAXED,
                                       __HIP_MEMORY_SCOPE_AGENT);
        }
      }
    }
  }
}

// ---------- LSE over k: scale partials, logsumexp, write log_resp ----------
__global__ void lse_k(float* __restrict__ out, const float* __restrict__ C,
                      float* __restrict__ partial) {
  const int row = blockIdx.x * 256 + threadIdx.x;
  float* w = out + 1 + (size_t)row * K_;
  float v[K_];
  float mx = -1e30f;
#pragma unroll
  for (int j = 0; j < K_; ++j) {
    v[j] = -0.5f * w[j] + C[j];
    mx = fmaxf(mx, v[j]);
  }
  float ssum = 0.f;
#pragma unroll
  for (int j = 0; j < K_; ++j) ssum += expf(v[j] - mx);
  float l = mx + logf(ssum);
#pragma unroll
  for (int j = 0; j < K_; ++j) w[j] = v[j] - l;
  __shared__ float red[256];
  red[threadIdx.x] = l;
  __syncthreads();
  for (int s = 128; s > 0; s >>= 1) {
    if (threadIdx.x < s) red[threadIdx.x] += red[threadIdx.x + s];
    __syncthreads();
  }
  if (threadIdx.x == 0) partial[blockIdx.x] = red[0];
}

__global__ void final_red(const float* __restrict__ partial,
                          float* __restrict__ out) {
  __shared__ float red[512];
  red[threadIdx.x] = partial[threadIdx.x];
  __syncthreads();
  for (int s = 256; s > 0; s >>= 1) {
    if (threadIdx.x < s) red[threadIdx.x] += red[threadIdx.x + s];
    __syncthreads();
  }
  if (threadIdx.x == 0) out[0] = red[0] * (1.0f / (float)N_);
}

extern "C" void kernel_launch(void* const* d_in, const int* in_sizes, int n_in,
                              void* d_out, int out_size, void* d_ws,
                              size_t ws_size, hipStream_t stream) {
  const float* X = (const float*)d_in[0];
  const float* w = (const float*)d_in[1];
  const float* mu = (const float*)d_in[2];
  const float* P = (const float*)d_in[3];
  float* out = (float*)d_out;
  char* ws = (char*)d_ws;

  // ws layout (bytes)
  ushort_t* Xb = (ushort_t*)ws;                         // 67,108,864
  ushort_t* Pb = (ushort_t*)(ws + 67108864);            // 8,388,608
  float* t = (float*)(ws + 75497472);                   // 65,536
  float* C = (float*)(ws + 75563008);                   // 256
  float* partial = (float*)(ws + 75563264);             // 2,048

  // zero the wlp accumulation region (out+1, N*K floats)
  hipMemsetAsync(out + 1, 0, (size_t)N_ * K_ * sizeof(float), stream);

  prep_x<<<2048, 256, 0, stream>>>(X, Xb);
  prep_p<<<2048, 256, 0, stream>>>(P, Pb);
  prep_t<<<K_, 256, 0, stream>>>(P, mu, w, t, C);
  gmm_main<<<NBLK, 512, 0, stream>>>(Xb, Pb, t, out + 1);
  lse_k<<<N_ / 256, 256, 0, stream>>>(out, C, partial);
  final_red<<<1, 512, 0, stream>>>(partial, out);
}

// Round 10
// 1850.207 us; speedup vs baseline: 3.0829x; 3.0829x over previous
//
#include <hip/hip_runtime.h>
#include <hip/hip_bf16.h>
#include <cmath>

// GMM E-step: N=131072, K=64, D=256.
// Round 10: round-9 structure with the circular-window ordering fixed:
// MFMAs consume Bw[f&15] BEFORE the prefetch for stream-frag +16
// overwrites that slot. A in regs (128 VGPR), B via 16-deep register
// window from L2, LDS only for the per-block sq accumulator (ds-atomic
// combine, zero barriers in the k-loop).

typedef unsigned short ushort_t;
typedef __attribute__((ext_vector_type(4))) float f32x4;
typedef __attribute__((ext_vector_type(8))) short bf16x8;

constexpr int N_ = 131072;
constexpr int K_ = 64;
constexpr int D_ = 256;
constexpr int BM = 128;                 // rows per block
constexpr int NBLK = N_ / BM;           // 1024 blocks
constexpr int SQLD = 68;                // padded sq row stride (floats)

// ---------- helpers ----------
__device__ __forceinline__ ushort_t f2bf(float v) {
  unsigned u = __float_as_uint(v);
  u += 0x7FFFu + ((u >> 16) & 1u);  // RNE
  return (ushort_t)(u >> 16);
}

// ---------- prep: X fp32 -> bf16 A-fragment image ----------
// e = ((T*8 + mm)*8 + kc)*512 + lane*8 + j  holds
//   bf16( X[T*128 + mm*16 + (lane&15)][kc*32 + (lane>>4)*8 + j] )
__global__ void prep_x(const float* __restrict__ X, ushort_t* __restrict__ Xb) {
  for (int e = blockIdx.x * blockDim.x + threadIdx.x; e < N_ * D_;
       e += gridDim.x * blockDim.x) {
    int j = e & 7;
    int lane = (e >> 3) & 63;
    int kc = (e >> 9) & 7;
    int mm = (e >> 12) & 7;
    int T = e >> 15;
    int row = T * 128 + mm * 16 + (lane & 15);
    int col = kc * 32 + (lane >> 4) * 8 + j;
    Xb[e] = f2bf(X[(size_t)row * D_ + col]);
  }
}

// ---------- prep: P fp32 -> bf16 B-fragment image (n-major order) ------
// e = (((k*4 + wc)*4 + n)*8 + ski)*512 + lane*8 + j  holds
//   bf16( P[k][ski*32 + (lane>>4)*8 + j][wc*64 + n*16 + (lane&15)] )
__global__ void prep_p(const float* __restrict__ P, ushort_t* __restrict__ Pb) {
  for (int e = blockIdx.x * blockDim.x + threadIdx.x; e < K_ * D_ * D_;
       e += gridDim.x * blockDim.x) {
    int j = e & 7;
    int lane = (e >> 3) & 63;
    int ski = (e >> 9) & 7;
    int n = (e >> 12) & 3;
    int wc = (e >> 14) & 3;
    int k = e >> 16;
    int row_p = ski * 32 + (lane >> 4) * 8 + j;
    int col_p = wc * 64 + n * 16 + (lane & 15);
    Pb[e] = f2bf(P[((size_t)k * D_ + row_p) * D_ + col_p]);
  }
}

// ---------- prep: t[k][j] = sum_i mu[k][i]*P[k][i][j];  C[k] ----------
__global__ void prep_t(const float* __restrict__ P, const float* __restrict__ mu,
                       const float* __restrict__ w, float* __restrict__ t,
                       float* __restrict__ C) {
  int k = blockIdx.x, j = threadIdx.x;
  const float* Pk = P + (size_t)k * D_ * D_;
  const float* muk = mu + (size_t)k * D_;
  float acc = 0.f;
  for (int i = 0; i < D_; ++i) acc += muk[i] * Pk[(size_t)i * D_ + j];
  t[k * D_ + j] = acc;
  __shared__ float red[D_];
  red[j] = logf(Pk[(size_t)j * D_ + j]);
  __syncthreads();
  for (int s = 128; s > 0; s >>= 1) {
    if (j < s) red[j] += red[j + s];
    __syncthreads();
  }
  if (j == 0)
    C[k] = red[0] + logf(w[k]) - 0.5f * (float)D_ * logf(2.0f * (float)M_PI);
}

// ---------- main: A in regs, B reg-window, LDS-atomic sq combine -------
__global__ __launch_bounds__(512, 2) void gmm_main(
    const ushort_t* __restrict__ Xb, const ushort_t* __restrict__ Pb,
    const float* __restrict__ tvec,
    float* __restrict__ wlp /* [N][K], raw sq written */) {
  __shared__ float sqf[BM * SQLD];  // 34.8 KiB padded accumulator

  const int tid = threadIdx.x;
  const int T = blockIdx.x;

  const int wid = tid >> 6, lane = tid & 63;
  const int wr = wid >> 2, wc = wid & 3;  // wave tile: 64 rows x 64 cols
  const int lc = lane & 15, lg = lane >> 4;

  // zero the sq accumulator (128*68 = 8704 floats, 17 per thread)
#pragma unroll
  for (int i = 0; i < 17; ++i) sqf[tid + i * 512] = 0.f;
  __syncthreads();

  // ---- A fragments in registers: 32 x bf16x8 = 128 VGPR ----
  const ushort_t* Ag = Xb + (size_t)T * 32768;
  bf16x8 Areg[32];  // index m*8 + ski
#pragma unroll
  for (int m = 0; m < 4; ++m)
#pragma unroll
    for (int c = 0; c < 8; ++c)
      Areg[m * 8 + c] =
          *(const bf16x8*)&Ag[(((wr * 4 + m) * 8 + c) * 512) + lane * 8];

  // ---- B window: 16 frags (64 VGPR), static circular indexing ----
  const ushort_t* Bbase = Pb + (size_t)wc * 16384 + lane * 8;
  bf16x8 Bw[16];
#pragma unroll
  for (int f = 0; f < 16; ++f)
    Bw[f] = *(const bf16x8*)(Bbase + (size_t)f * 512);

#pragma unroll 1
  for (int k = 0; k < K_; ++k) {
    float tv[4];
#pragma unroll
    for (int n = 0; n < 4; ++n) tv[n] = tvec[k * D_ + wc * 64 + n * 16 + lc];

    f32x4 sqa[4];
#pragma unroll
    for (int m = 0; m < 4; ++m) sqa[m] = (f32x4){0.f, 0.f, 0.f, 0.f};

#pragma unroll
    for (int n = 0; n < 4; ++n) {
      f32x4 accg[4];
#pragma unroll
      for (int m = 0; m < 4; ++m) accg[m] = (f32x4){0.f, 0.f, 0.f, 0.f};
#pragma unroll
      for (int ski = 0; ski < 8; ++ski) {
        const int f = n * 8 + ski;
        // CONSUME first: 4 MFMAs read Bw[f&15] (stream frag k*32+f) ...
#pragma unroll
        for (int m = 0; m < 4; ++m)
          accg[m] = __builtin_amdgcn_mfma_f32_16x16x32_bf16(
              Areg[m * 8 + ski], Bw[f & 15], accg[m], 0, 0, 0);
        // ... THEN prefetch stream frag k*32+f+16 into the same slot.
        // WAR on Bw[f&15] orders the load after the MFMA reads; it has
        // 16 frag-steps (~310 cyc of MFMA issue) to return.
        if (k * 32 + f + 16 < K_ * 32) {
          const int gf = k * 32 + f + 16;
          const int kk = gf >> 5, ff = gf & 31;
          Bw[f & 15] =
              *(const bf16x8*)(Bbase + (size_t)kk * 65536 + (size_t)ff * 512);
        }
      }
      // fold this col-group into the running sq partial
#pragma unroll
      for (int m = 0; m < 4; ++m)
#pragma unroll
        for (int r = 0; r < 4; ++r) {
          float d = accg[m][r] - tv[n];
          sqa[m][r] += d * d;
        }
    }

    // cross-lane reduce over lc (cols), then LDS atomic add (no barrier)
#pragma unroll
    for (int m = 0; m < 4; ++m)
#pragma unroll
      for (int r = 0; r < 4; ++r) {
        float sfl = sqa[m][r];
        sfl += __shfl_xor(sfl, 1, 64);
        sfl += __shfl_xor(sfl, 2, 64);
        sfl += __shfl_xor(sfl, 4, 64);
        sfl += __shfl_xor(sfl, 8, 64);
        if (lc == 0) {
          int row = wr * 64 + m * 16 + lg * 4 + r;
          atomicAdd(&sqf[row * SQLD + k], sfl);
        }
      }
  }

  __syncthreads();  // all waves' ds_adds complete

  // flush: sq[128][64] -> wlp, coalesced f32x4
  float* dst = wlp + (size_t)T * BM * K_;
#pragma unroll
  for (int i = 0; i < 4; ++i) {
    int idx4 = tid + i * 512;          // 2048 f32x4 total
    int row = idx4 >> 4, c4 = idx4 & 15;
    ((f32x4*)dst)[idx4] = *(const f32x4*)&sqf[row * SQLD + c4 * 4];
  }
}

// ---------- LSE over k: scale partials, logsumexp, write log_resp ------
__global__ void lse_k(float* __restrict__ out, const float* __restrict__ C,
                      float* __restrict__ partial) {
  const int row = blockIdx.x * 256 + threadIdx.x;
  float* w = out + 1 + (size_t)row * K_;
  float v[K_];
  float mx = -1e30f;
#pragma unroll
  for (int j = 0; j < K_; ++j) {
    v[j] = -0.5f * w[j] + C[j];
    mx = fmaxf(mx, v[j]);
  }
  float ssum = 0.f;
#pragma unroll
  for (int j = 0; j < K_; ++j) ssum += expf(v[j] - mx);
  float l = mx + logf(ssum);
#pragma unroll
  for (int j = 0; j < K_; ++j) w[j] = v[j] - l;
  __shared__ float red[256];
  red[threadIdx.x] = l;
  __syncthreads();
  for (int s = 128; s > 0; s >>= 1) {
    if (threadIdx.x < s) red[threadIdx.x] += red[threadIdx.x + s];
    __syncthreads();
  }
  if (threadIdx.x == 0) partial[blockIdx.x] = red[0];
}

__global__ void final_red(const float* __restrict__ partial,
                          float* __restrict__ out) {
  __shared__ float red[512];
  red[threadIdx.x] = partial[threadIdx.x];
  __syncthreads();
  for (int s = 256; s > 0; s >>= 1) {
    if (threadIdx.x < s) red[threadIdx.x] += red[threadIdx.x + s];
    __syncthreads();
  }
  if (threadIdx.x == 0) out[0] = red[0] * (1.0f / (float)N_);
}

extern "C" void kernel_launch(void* const* d_in, const int* in_sizes, int n_in,
                              void* d_out, int out_size, void* d_ws,
                              size_t ws_size, hipStream_t stream) {
  const float* X = (const float*)d_in[0];
  const float* w = (const float*)d_in[1];
  const float* mu = (const float*)d_in[2];
  const float* P = (const float*)d_in[3];
  float* out = (float*)d_out;
  char* ws = (char*)d_ws;

  // ws layout (bytes)
  ushort_t* Xb = (ushort_t*)ws;                         // 67,108,864
  ushort_t* Pb = (ushort_t*)(ws + 67108864);            // 8,388,608
  float* t = (float*)(ws + 75497472);                   // 65,536
  float* C = (float*)(ws + 75563008);                   // 256
  float* partial = (float*)(ws + 75563264);             // 2,048

  prep_x<<<2048, 256, 0, stream>>>(X, Xb);
  prep_p<<<2048, 256, 0, stream>>>(P, Pb);
  prep_t<<<K_, 256, 0, stream>>>(P, mu, w, t, C);
  gmm_main<<<NBLK, 512, 0, stream>>>(Xb, Pb, t, out + 1);
  lse_k<<<N_ / 256, 256, 0, stream>>>(out, C, partial);
  final_red<<<1, 512, 0, stream>>>(partial, out);
}

// Round 11
// 1016.898 us; speedup vs baseline: 5.6091x; 1.8195x over previous
//
#include <hip/hip_runtime.h>
#include <hip/hip_bf16.h>
#include <cmath>

// GMM E-step: N=131072, K=64, D=256.
// Round 11: A in registers (128 VGPR); B staged via global_load_lds into
// a 4-buffer BK=32 ring, staged 2 ahead, counted s_waitcnt vmcnt(4)
// (never drained in the loop). Epilogue reduction via DPP v_add (VALU
// pipe, not ds_bpermute); cross-wave combine via ds_add_f32. tvec lives
// in LDS as bf16 so the k-loop has zero non-staging vmem.

typedef unsigned short ushort_t;
typedef __attribute__((ext_vector_type(4))) float f32x4;
typedef __attribute__((ext_vector_type(8))) short bf16x8;

constexpr int N_ = 131072;
constexpr int K_ = 64;
constexpr int D_ = 256;
constexpr int BM = 128;                 // rows per block
constexpr int NBLK = N_ / BM;           // 1024 blocks
constexpr int SQLD = 68;                // padded sq row stride (floats)

// ---------- helpers ----------
__device__ __forceinline__ ushort_t f2bf(float v) {
  unsigned u = __float_as_uint(v);
  u += 0x7FFFu + ((u >> 16) & 1u);  // RNE
  return (ushort_t)(u >> 16);
}

__device__ __forceinline__ void gld16(const ushort_t* g, ushort_t* l) {
  __builtin_amdgcn_global_load_lds(
      (const __attribute__((address_space(1))) unsigned int*)g,
      (__attribute__((address_space(3))) unsigned int*)l, 16, 0, 0);
}

// 16-lane (lc-group) sum, VALU-only: xor1, xor2 (quad_perm), then
// ROW_HALF_MIRROR (pairs quads) and ROW_MIRROR (pairs 8-halves).
__device__ __forceinline__ float dpp_red16(float v) {
  int x = __float_as_int(v);
  v += __int_as_float(__builtin_amdgcn_update_dpp(0, x, 0xB1, 0xF, 0xF, true));
  x = __float_as_int(v);
  v += __int_as_float(__builtin_amdgcn_update_dpp(0, x, 0x4E, 0xF, 0xF, true));
  x = __float_as_int(v);
  v += __int_as_float(__builtin_amdgcn_update_dpp(0, x, 0x141, 0xF, 0xF, true));
  x = __float_as_int(v);
  v += __int_as_float(__builtin_amdgcn_update_dpp(0, x, 0x140, 0xF, 0xF, true));
  return v;
}

// ---------- prep: X fp32 -> bf16 A-fragment image ----------
// e = ((T*8 + mm)*8 + kc)*512 + lane*8 + j  holds
//   bf16( X[T*128 + mm*16 + (lane&15)][kc*32 + (lane>>4)*8 + j] )
__global__ void prep_x(const float* __restrict__ X, ushort_t* __restrict__ Xb) {
  for (int e = blockIdx.x * blockDim.x + threadIdx.x; e < N_ * D_;
       e += gridDim.x * blockDim.x) {
    int j = e & 7;
    int lane = (e >> 3) & 63;
    int kc = (e >> 9) & 7;
    int mm = (e >> 12) & 7;
    int T = e >> 15;
    int row = T * 128 + mm * 16 + (lane & 15);
    int col = kc * 32 + (lane >> 4) * 8 + j;
    Xb[e] = f2bf(X[(size_t)row * D_ + col]);
  }
}

// ---------- prep: P fp32 -> bf16 B substep image (BK=32) ----------
// e = (g*16 + wc*4 + n)*512 + lane*8 + j,  g = k*8 + s,  holds
//   bf16( P[k][s*32 + (lane>>4)*8 + j][wc*64 + n*16 + (lane&15)] )
__global__ void prep_p(const float* __restrict__ P, ushort_t* __restrict__ Pb) {
  for (int e = blockIdx.x * blockDim.x + threadIdx.x; e < K_ * D_ * D_;
       e += gridDim.x * blockDim.x) {
    int j = e & 7;
    int lane = (e >> 3) & 63;
    int n = (e >> 9) & 3;
    int wc = (e >> 11) & 3;
    int g = e >> 13;
    int k = g >> 3, s = g & 7;
    int row_p = s * 32 + (lane >> 4) * 8 + j;
    int col_p = wc * 64 + n * 16 + (lane & 15);
    Pb[e] = f2bf(P[((size_t)k * D_ + row_p) * D_ + col_p]);
  }
}

// ---------- prep: tvb[k][j] = bf16(sum_i mu[k][i]*P[k][i][j]); C[k] ----
__global__ void prep_t(const float* __restrict__ P, const float* __restrict__ mu,
                       const float* __restrict__ w, ushort_t* __restrict__ tvb,
                       float* __restrict__ C) {
  int k = blockIdx.x, j = threadIdx.x;
  const float* Pk = P + (size_t)k * D_ * D_;
  const float* muk = mu + (size_t)k * D_;
  float acc = 0.f;
  for (int i = 0; i < D_; ++i) acc += muk[i] * Pk[(size_t)i * D_ + j];
  tvb[k * D_ + j] = f2bf(acc);
  __shared__ float red[D_];
  red[j] = logf(Pk[(size_t)j * D_ + j]);
  __syncthreads();
  for (int s = 128; s > 0; s >>= 1) {
    if (j < s) red[j] += red[j + s];
    __syncthreads();
  }
  if (j == 0)
    C[k] = red[0] + logf(w[k]) - 0.5f * (float)D_ * logf(2.0f * (float)M_PI);
}

// ---------- main ----------
__global__ __launch_bounds__(512, 2) void gmm_main(
    const ushort_t* __restrict__ Xb, const ushort_t* __restrict__ Pb,
    const ushort_t* __restrict__ tvb,
    float* __restrict__ wlp /* [N][K], raw sq written */) {
  __shared__ __align__(16) ushort_t Bl[4][8192];  // 64 KiB, BK=32 ring
  __shared__ __align__(16) ushort_t tvl[16384];   // 32 KiB bf16 tvec
  __shared__ float sqf[BM * SQLD];                // 34.8 KiB accumulator

  const int tid = threadIdx.x;
  const int T = blockIdx.x;
  const int lane = tid & 63, wid = tid >> 6;
  const int wr = wid >> 2, wc = wid & 3;  // wave tile: 64 rows x 64 cols
  const int lc = lane & 15, lg = lane >> 4;

  // zero sq accumulator (128*68 = 8704 floats, 17/thread)
#pragma unroll
  for (int i = 0; i < 17; ++i) sqf[tid + i * 512] = 0.f;

  // ---- A fragments in registers: 32 x bf16x8 = 128 VGPR ----
  const ushort_t* Ag = Xb + (size_t)T * 32768;
  bf16x8 Areg[32];  // index m*8 + s (s = 32-wide k-chunk)
#pragma unroll
  for (int m = 0; m < 4; ++m)
#pragma unroll
    for (int c = 0; c < 8; ++c)
      Areg[m * 8 + c] =
          *(const bf16x8*)&Ag[(((wr * 4 + m) * 8 + c) * 512) + lane * 8];

  // ---- stage tvec (32 KB) + B substeps g=0,1 ----
#pragma unroll
  for (int it = 0; it < 4; ++it)
    gld16(tvb + (it * 512 + tid) * 8, &tvl[(it * 512 + tid) * 8]);
#pragma unroll
  for (int it = 0; it < 2; ++it)
    gld16(Pb + (it * 512 + tid) * 8, &Bl[0][(it * 512 + tid) * 8]);
#pragma unroll
  for (int it = 0; it < 2; ++it)
    gld16(Pb + 8192 + (it * 512 + tid) * 8, &Bl[1][(it * 512 + tid) * 8]);

  asm volatile("s_waitcnt vmcnt(0) lgkmcnt(0)" ::: "memory");
  __builtin_amdgcn_s_barrier();

#pragma unroll 1
  for (int k = 0; k < K_; ++k) {
    f32x4 acc[4][4];
#pragma unroll
    for (int m = 0; m < 4; ++m)
#pragma unroll
      for (int n = 0; n < 4; ++n) acc[m][n] = (f32x4){0.f, 0.f, 0.f, 0.f};

#pragma unroll
    for (int s = 0; s < 8; ++s) {
      // stage substep g+2 (Pb has 2 substeps of slack, so no branch)
      const int g2 = k * 8 + s + 2;
      const ushort_t* gb = Pb + (size_t)g2 * 8192;
      ushort_t* db = &Bl[(s + 2) & 3][0];
#pragma unroll
      for (int it = 0; it < 2; ++it)
        gld16(gb + (it * 512 + tid) * 8, db + (it * 512 + tid) * 8);
      // counted wait: substep s's 2 loads done; s+1, s+2 stay in flight
      asm volatile("s_waitcnt vmcnt(4)" ::: "memory");
      __builtin_amdgcn_s_barrier();

      bf16x8 bb[4];
#pragma unroll
      for (int n = 0; n < 4; ++n)
        bb[n] = *(const bf16x8*)&Bl[s & 3][(wc * 4 + n) * 512 + lane * 8];
#pragma unroll
      for (int m = 0; m < 4; ++m)
#pragma unroll
        for (int n = 0; n < 4; ++n)
          acc[m][n] = __builtin_amdgcn_mfma_f32_16x16x32_bf16(
              Areg[m * 8 + s], bb[n], acc[m][n], 0, 0, 0);
    }

    // epilogue: VALU-only 16-lane reduce, ds_add combine (no barrier)
    float tv[4];
#pragma unroll
    for (int n = 0; n < 4; ++n) {
      ushort_t uv = tvl[k * 256 + wc * 64 + n * 16 + lc];
      tv[n] = __uint_as_float((unsigned)uv << 16);
    }
#pragma unroll
    for (int m = 0; m < 4; ++m)
#pragma unroll
      for (int r = 0; r < 4; ++r) {
        float d0 = acc[m][0][r] - tv[0];
        float d1 = acc[m][1][r] - tv[1];
        float d2 = acc[m][2][r] - tv[2];
        float d3 = acc[m][3][r] - tv[3];
        float sfl = dpp_red16(d0 * d0 + d1 * d1 + d2 * d2 + d3 * d3);
        if (lc == 0) {
          int row = wr * 64 + m * 16 + lg * 4 + r;
          atomicAdd(&sqf[row * SQLD + k], sfl);
        }
      }
  }

  __syncthreads();  // all ds_adds visible

  // flush: sq[128][64] -> wlp, coalesced f32x4
  float* dst = wlp + (size_t)T * BM * K_;
#pragma unroll
  for (int i = 0; i < 4; ++i) {
    int idx4 = tid + i * 512;
    int row = idx4 >> 4, c4 = idx4 & 15;
    ((f32x4*)dst)[idx4] = *(const f32x4*)&sqf[row * SQLD + c4 * 4];
  }
}

// ---------- LSE over k: scale partials, logsumexp, write log_resp ------
__global__ void lse_k(float* __restrict__ out, const float* __restrict__ C,
                      float* __restrict__ partial) {
  const int row = blockIdx.x * 256 + threadIdx.x;
  float* w = out + 1 + (size_t)row * K_;
  float v[K_];
  float mx = -1e30f;
#pragma unroll
  for (int j = 0; j < K_; ++j) {
    v[j] = -0.5f * w[j] + C[j];
    mx = fmaxf(mx, v[j]);
  }
  float ssum = 0.f;
#pragma unroll
  for (int j = 0; j < K_; ++j) ssum += expf(v[j] - mx);
  float l = mx + logf(ssum);
#pragma unroll
  for (int j = 0; j < K_; ++j) w[j] = v[j] - l;
  __shared__ float red[256];
  red[threadIdx.x] = l;
  __syncthreads();
  for (int s = 128; s > 0; s >>= 1) {
    if (threadIdx.x < s) red[threadIdx.x] += red[threadIdx.x + s];
    __syncthreads();
  }
  if (threadIdx.x == 0) partial[blockIdx.x] = red[0];
}

__global__ void final_red(const float* __restrict__ partial,
                          float* __restrict__ out) {
  __shared__ float red[512];
  red[threadIdx.x] = partial[threadIdx.x];
  __syncthreads();
  for (int s = 256; s > 0; s >>= 1) {
    if (threadIdx.x < s) red[threadIdx.x] += red[threadIdx.x + s];
    __syncthreads();
  }
  if (threadIdx.x == 0) out[0] = red[0] * (1.0f / (float)N_);
}

extern "C" void kernel_launch(void* const* d_in, const int* in_sizes, int n_in,
                              void* d_out, int out_size, void* d_ws,
                              size_t ws_size, hipStream_t stream) {
  const float* X = (const float*)d_in[0];
  const float* w = (const float*)d_in[1];
  const float* mu = (const float*)d_in[2];
  const float* P = (const float*)d_in[3];
  float* out = (float*)d_out;
  char* ws = (char*)d_ws;

  // ws layout (bytes) — total 75,565,312 (same as prior rounds)
  ushort_t* Xb = (ushort_t*)ws;                 // 67,108,864
  ushort_t* Pb = (ushort_t*)(ws + 67108864);    // 8,388,608 + 32,768 slack
  ushort_t* tvb = (ushort_t*)(ws + 75530240);   // 32,768 (bf16 tvec)
  float* C = (float*)(ws + 75563008);           // 256
  float* partial = (float*)(ws + 75563264);     // 2,048

  prep_x<<<2048, 256, 0, stream>>>(X, Xb);
  prep_p<<<2048, 256, 0, stream>>>(P, Pb);
  prep_t<<<K_, 256, 0, stream>>>(P, mu, w, tvb, C);
  gmm_main<<<NBLK, 512, 0, stream>>>(Xb, Pb, tvb, out + 1);
  lse_k<<<N_ / 256, 256, 0, stream>>>(out, C, partial);
  final_red<<<1, 512, 0, stream>>>(partial, out);
}